// Round 5
// baseline (293.631 us; speedup 1.0000x reference)
//
#include <hip/hip_runtime.h>
#include <math.h>

#define OUT 7
#define NVOX 343        // 7*7*7
#define LDSF 11520      // staged data floats (45 KB)
#define ROWCAP 1792     // row-offset table entries (7 KB); total LDS 52 KB -> 3 blocks/CU
#define CPG 2           // channels per block
#define BLK 512         // 8 waves

__device__ __forceinline__ void axis_samp(float c, float fdim, int dim,
                                          int& lo, float& w0, float& w1) {
    float valid = (c > -1.0f && c < fdim) ? 1.0f : 0.0f;
    float cc = fminf(fmaxf(c, 0.0f), fdim - 1.0f);
    lo = (int)floorf(cc);
    float fr = cc - (float)lo;
    w0 = (1.0f - fr) * valid;
    w1 = fr * valid;     // == 0 whenever hi would be clamped (fr==0 at lo==dim-1)
}

__global__ __launch_bounds__(BLK) void roi_align_ms3d_kernel(
    const float* __restrict__ f0, const float* __restrict__ f1,
    const float* __restrict__ f2, const float* __restrict__ f3,
    const float* __restrict__ boxes, float* __restrict__ out,
    int N, int C, int d0, int d1, int d2_, int d3)
{
    __shared__ float lds[LDSF];
    __shared__ int rowsrc[ROWCAP];

    const int g   = blockIdx.x;   // channel group (CPG channels)
    const int n   = blockIdx.y;   // box
    const int tid = threadIdx.x;

    const float* bp = boxes + n * 6;
    float b0 = bp[0], b1 = bp[1], b2 = bp[2];
    float b3 = bp[3], b4 = bp[4], b5 = bp[5];

    // level_map
    float vol = (b3 - b0) * (b4 - b1) * (b5 - b2);
    float s = cbrtf(vol);
    float lvl = floorf(4.0f + log2f(s / 160.0f) + 1e-6f);
    lvl = fminf(fmaxf(lvl, 2.0f), 5.0f);
    int l = (int)lvl - 2;

    const float* f;
    int dim;
    float scale;
    if (l == 0)      { f = f0; dim = d0;  scale = 0.25f;    }
    else if (l == 1) { f = f1; dim = d1;  scale = 0.125f;   }
    else if (l == 2) { f = f2; dim = d2_; scale = 0.0625f;  }
    else             { f = f3; dim = d3;  scale = 0.03125f; }

    const float fdim = (float)dim;
    const int dsq = dim * dim;
    const size_t dcube = (size_t)dim * dsq;
    const float* fbase = f + (size_t)(g * CPG) * dcube;

    float sx = b0 * scale, sy = b1 * scale, sz = b2 * scale;
    float szx = fmaxf(b3 * scale - sx, 1.0f);
    float szy = fmaxf(b4 * scale - sy, 1.0f);
    float szz = fmaxf(b5 * scale - sz, 1.0f);
    float bx = szx * (1.0f / OUT), by = szy * (1.0f / OUT), bz = szz * (1.0f / OUT);

    // Lattice region touched by any clipped sub-sample:
    // sample coords span [start + 0.25*b, start + 6.75*b]
    int x0 = (int)floorf(fminf(fmaxf(sx + 0.25f * bx, 0.0f), fdim - 1.0f));
    int x1 = min((int)floorf(fminf(fmaxf(sx + 6.75f * bx, 0.0f), fdim - 1.0f)) + 1, dim - 1);
    int y0 = (int)floorf(fminf(fmaxf(sy + 0.25f * by, 0.0f), fdim - 1.0f));
    int y1 = min((int)floorf(fminf(fmaxf(sy + 6.75f * by, 0.0f), fdim - 1.0f)) + 1, dim - 1);
    int z0 = (int)floorf(fminf(fmaxf(sz + 0.25f * bz, 0.0f), fdim - 1.0f));
    int z1 = min((int)floorf(fminf(fmaxf(sz + 6.75f * bz, 0.0f), fdim - 1.0f)) + 1, dim - 1);

    int nx = x1 - x0 + 1, ny = y1 - y0 + 1, nz = z1 - z0 + 1;
    int pitch = (nz + 1) | 1;        // >= nz+1, odd -> bank-conflict-friendly
    int nynzp = ny * pitch;
    int nrows = nx * ny;
    int nregp = nrows * pitch;

    // Per-voxel axis data (one voxel per thread; channel-invariant)
    int xl[2], yl[2], zl[2];
    float xw0[2], xw1[2], yw0[2], yw1[2], zw0[2], zw1[2];
    if (tid < NVOX) {
        int oz = tid % OUT;
        int oy = (tid / OUT) % OUT;
        int ox = tid / (OUT * OUT);
        #pragma unroll
        for (int r = 0; r < 2; ++r) {
            float off = 0.25f + 0.5f * (float)r;
            axis_samp(sx + ((float)ox + off) * bx, fdim, dim, xl[r], xw0[r], xw1[r]);
            axis_samp(sy + ((float)oy + off) * by, fdim, dim, yl[r], yw0[r], yw1[r]);
            axis_samp(sz + ((float)oz + off) * bz, fdim, dim, zl[r], zw0[r], zw1[r]);
        }
    }

    float* outp = out + ((size_t)n * C + g * CPG) * NVOX + tid;

    if (nregp <= LDSF && nrows <= ROWCAP) {
        // ---- fill channel-invariant row-offset table (once per block) ----
        float rny = 1.0f / (float)ny;
        for (int row = tid; row < nrows; row += BLK) {
            int rx = (int)((float)row * rny);
            int ry = row - rx * ny;
            if (ry < 0)        { rx -= 1; ry += ny; }
            else if (ry >= ny) { rx += 1; ry -= ny; }
            rowsrc[row] = ((x0 + rx) * dim + (y0 + ry)) * dim + z0;
        }

        // Hoisted channel-invariant interp bases
        int XL[2], XH[2], YL[2], YH[2], ZL[2];
        if (tid < NVOX) {
            #pragma unroll
            for (int r = 0; r < 2; ++r) {
                XL[r] = (xl[r] - x0) * nynzp;
                XH[r] = (min(xl[r] + 1, dim - 1) - x0) * nynzp;
                YL[r] = (yl[r] - y0) * pitch;
                YH[r] = (min(yl[r] + 1, dim - 1) - y0) * pitch;
                ZL[r] = zl[r] - z0;
            }
        }
        __syncthreads();

        const int lane16 = tid & 15;
        const int grp16  = tid >> 4;

        for (int ci = 0; ci < CPG; ++ci) {
            const float* fcc = fbase + (size_t)ci * dcube;

            // ---- stage: 16 lanes per region row, coalesced z-runs ----
            for (int rg = grp16; rg < nrows; rg += (BLK / 16)) {
                const float* src = fcc + rowsrc[rg];
                float* dst = lds + rg * pitch;
                for (int zz = lane16; zz < pitch; zz += 16)
                    dst[zz] = src[min(zz, nz - 1)];   // pad dups last z (finite; weight 0)
            }
            __syncthreads();

            if (tid < NVOX) {
                float acc = 0.0f;
                #pragma unroll
                for (int rx2 = 0; rx2 < 2; ++rx2) {
                    #pragma unroll
                    for (int ry2 = 0; ry2 < 2; ++ry2) {
                        #pragma unroll
                        for (int rz2 = 0; rz2 < 2; ++rz2) {
                            const float* pll = lds + (XL[rx2] + YL[ry2] + ZL[rz2]);
                            const float* plh = lds + (XL[rx2] + YH[ry2] + ZL[rz2]);
                            const float* phl = lds + (XH[rx2] + YL[ry2] + ZL[rz2]);
                            const float* phh = lds + (XH[rx2] + YH[ry2] + ZL[rz2]);
                            float v000 = pll[0], v001 = pll[1];
                            float v010 = plh[0], v011 = plh[1];
                            float v100 = phl[0], v101 = phl[1];
                            float v110 = phh[0], v111 = phh[1];
                            float wz0 = zw0[rz2], wz1 = zw1[rz2];
                            float vx0 = yw0[ry2] * (wz0 * v000 + wz1 * v001)
                                      + yw1[ry2] * (wz0 * v010 + wz1 * v011);
                            float vx1 = yw0[ry2] * (wz0 * v100 + wz1 * v101)
                                      + yw1[ry2] * (wz0 * v110 + wz1 * v111);
                            acc += xw0[rx2] * vx0 + xw1[rx2] * vx1;
                        }
                    }
                }
                outp[ci * NVOX] = acc * 0.125f;
            }
            if (ci + 1 < CPG) __syncthreads();
        }
    } else {
        // ---- safety net (rare pancake boxes): direct global loads ----
        if (tid < NVOX) {
            for (int ci = 0; ci < CPG; ++ci) {
                const float* fcc = fbase + (size_t)ci * dcube;
                float acc = 0.0f;
                #pragma unroll
                for (int rx2 = 0; rx2 < 2; ++rx2) {
                    const float* pxl = fcc + (size_t)xl[rx2] * dsq;
                    const float* pxh = fcc + (size_t)min(xl[rx2] + 1, dim - 1) * dsq;
                    float wx0 = xw0[rx2], wx1 = xw1[rx2];
                    #pragma unroll
                    for (int ry2 = 0; ry2 < 2; ++ry2) {
                        int ryl = yl[ry2] * dim;
                        int ryh = min(yl[ry2] + 1, dim - 1) * dim;
                        float wy0 = yw0[ry2], wy1 = yw1[ry2];
                        #pragma unroll
                        for (int rz2 = 0; rz2 < 2; ++rz2) {
                            int bZL = zl[rz2];
                            int bZH = min(zl[rz2] + 1, dim - 1);
                            float wz0 = zw0[rz2], wz1 = zw1[rz2];
                            float v000 = pxl[ryl + bZL];
                            float v001 = pxl[ryl + bZH];
                            float v010 = pxl[ryh + bZL];
                            float v011 = pxl[ryh + bZH];
                            float v100 = pxh[ryl + bZL];
                            float v101 = pxh[ryl + bZH];
                            float v110 = pxh[ryh + bZL];
                            float v111 = pxh[ryh + bZH];
                            float vx0 = wy0 * (wz0 * v000 + wz1 * v001)
                                      + wy1 * (wz0 * v010 + wz1 * v011);
                            float vx1 = wy0 * (wz0 * v100 + wz1 * v101)
                                      + wy1 * (wz0 * v110 + wz1 * v111);
                            acc += wx0 * vx0 + wx1 * vx1;
                        }
                    }
                }
                outp[ci * NVOX] = acc * 0.125f;
            }
        }
    }
}

extern "C" void kernel_launch(void* const* d_in, const int* in_sizes, int n_in,
                              void* d_out, int out_size, void* d_ws, size_t ws_size,
                              hipStream_t stream) {
    const float* f0 = (const float*)d_in[0];
    const float* f1 = (const float*)d_in[1];
    const float* f2 = (const float*)d_in[2];
    const float* f3 = (const float*)d_in[3];
    const float* boxes = (const float*)d_in[4];
    float* out = (float*)d_out;

    int N = in_sizes[4] / 6;
    int C = out_size / (N * NVOX);

    auto cdim = [&](int sz) {
        int per_c = sz / C;
        return (int)(cbrtf((float)per_c) + 0.5f);
    };
    int d0 = cdim(in_sizes[0]);
    int d1 = cdim(in_sizes[1]);
    int d2 = cdim(in_sizes[2]);
    int d3 = cdim(in_sizes[3]);

    dim3 grid(C / CPG, N);   // one block per (box, channel-pair)
    roi_align_ms3d_kernel<<<grid, BLK, 0, stream>>>(f0, f1, f2, f3, boxes, out,
                                                    N, C, d0, d1, d2, d3);
}